// Round 3
// baseline (62170.880 us; speedup 1.0000x reference)
//
#include <hip/hip_runtime.h>

#define HIDDEN   2048
#define T_STEPS  8192
#define WASHOUT  200
#define NWG      64
#define NTHR     512
#define NWAVE    (NTHR / 64)                 // 8 waves
#define ROWS_PER_WG   (HIDDEN / NWG)         // 32
#define ROWS_PER_WAVE (ROWS_PER_WG / NWAVE)  // 4
#define NCHUNK   8                           // 8 chunks of 256 state elements
#define NBLK_CLAIM 512
#define POISON   0xAAAAAAAAu

// ws layout: unsigned long long pairs[2][HIDDEN] (32 KB) -- {value:hi32,
// step:lo32}; then unsigned ctl[2] at byte 32768: {target_xcc, claim_ctr},
// both relying on 0xAA poison as the "unset" state. Worker 0 re-poisons ctl
// at kernel end so graph replays start clean. Mailbox tags self-correct
// across dispatches (stale tags never match the current want sequence).
//
// R16 (this round): SINGLE-XCD residency. R2's nt experiment proved polls
// are served from the poller's local L2 (FETCH_SIZE unmoved at ~70KB/step)
// and the cost is the writer's cross-XCD probe/invalidate + refetch
// (~1.4us/step of the 2.15us). Fix: co-locate all 64 WGs on ONE XCD
// (2 WGs/CU on 32 CUs) so the mailbox lives in one shared L2. Blocks read
// HW_REG_XCC_ID; first block CASes its XCD into ctl[0]; same-XCD blocks
// claim slots 0..63; others exit. Compute per CU doubles (~+0.3us) but the
// visibility hop becomes an L2 round trip (~-1.1us predicted).
// R2 lesson kept: polls stay sc1 (L2-cacheable), NO nt.
// R1 lesson kept: consolidated 256B publish by wave 0 (scattered stores
// cost more ownership transactions).

// DPP add: x + dpp_perm(x). All-VALU (no DS round trip).
#define DPP_ADD(x, ctrl) ((x) + __int_as_float(__builtin_amdgcn_update_dpp( \
    0, __float_as_int(x), ctrl, 0xF, 0xF, true)))

typedef unsigned uint4v __attribute__((ext_vector_type(4)));

__global__ __launch_bounds__(NTHR, 4) void esn_main(
    const float* __restrict__ u,
    const float* __restrict__ w_in,
    const float* __restrict__ w_res,
    const float* __restrict__ w_out,
    float* __restrict__ out,
    unsigned long long* __restrict__ pairs,
    int use_claim)
{
  const int j  = threadIdx.x;   // 0..511
  const int wv = j >> 6;        // 0..7
  const int l  = j & 63;

  unsigned* ctl = (unsigned*)(pairs + 2 * HIDDEN);
  __shared__ unsigned s_slot;

  if (use_claim) {
    if (j == 0) {
      unsigned my_x;
      asm volatile("s_getreg_b32 %0, hwreg(HW_REG_XCC_ID)" : "=s"(my_x));
      // first block anywhere nominates its own XCD as the target
      const unsigned old = atomicCAS(&ctl[0], POISON, my_x);
      const unsigned tgt = (old == POISON) ? my_x : old;
      unsigned slot = 0xFFFFFFFFu;
      if (my_x == tgt) slot = atomicAdd(&ctl[1], 1u) - POISON;
      s_slot = slot;
    }
    __syncthreads();
  } else {
    if (j == 0) s_slot = blockIdx.x;
    __syncthreads();
  }
  const unsigned g = s_slot;     // logical WG id 0..63
  if (g >= NWG) return;          // off-target or surplus block

  __shared__ float x_s[2][HIDDEN];      // double-buffered staged state (16 KB)
  __shared__ float u_s[T_STEPS];        // 32 KB
  __shared__ float fresh[ROWS_PER_WG];  // this WG's newest 32 values

#pragma unroll
  for (int k = 0; k < T_STEPS / NTHR; ++k) u_s[j + NTHR * k] = u[j + NTHR * k];

  // wave wv owns rows r0..r0+3; lane l owns cols {c*256 + 4l .. +3}
  const int r0 = g * ROWS_PER_WG + wv * ROWS_PER_WAVE;

  float wreg[ROWS_PER_WAVE][4 * NCHUNK];  // 128 register-resident weights
#pragma unroll
  for (int i = 0; i < ROWS_PER_WAVE; ++i) {
#pragma unroll
    for (int c = 0; c < NCHUNK; ++c) {
      const float4 a = *(const float4*)&w_res[(r0 + i) * HIDDEN + c * 256 + 4 * l];
      wreg[i][4 * c + 0] = a.x; wreg[i][4 * c + 1] = a.y;
      wreg[i][4 * c + 2] = a.z; wreg[i][4 * c + 3] = a.w;
    }
  }
  // pin weights; value becomes opaque -> no refetch, no remat in t-loop
#pragma unroll
  for (int i = 0; i < ROWS_PER_WAVE; ++i)
#pragma unroll
    for (int k = 0; k < 4 * NCHUNK; ++k)
      asm volatile("" : "+v"(wreg[i][k]));

  const float winl = w_in[r0 + (l & 3)];                             // lanes 0..3
  const float wol  = (wv == 1 && l < 32) ? w_out[g * 32 + l] : 0.f;  // wave 1

  __syncthreads();  // u_s ready

  for (int t = 0; t < T_STEPS; ++t) {
    float d0 = 0.f, d1 = 0.f, d2 = 0.f, d3 = 0.f;
    const unsigned b = (unsigned)((t - 1) & 1);
    if (t > 0) {
      const unsigned want = (unsigned)(t - 1);
      // wave wv polls only its own chunk; 2x16B sc1 loads (L2-served spin)
      const unsigned long long* bp = pairs + b * HIDDEN + (wv << 8) + 4 * l;
      uint4v A, B;   // [tag0, val0, tag1, val1]
      for (;;) {
        asm volatile(
            "global_load_dwordx4 %0, %2, off sc1\n\t"
            "global_load_dwordx4 %1, %3, off sc1\n\t"
            "s_waitcnt vmcnt(0)"
            : "=&v"(A), "=&v"(B)
            : "v"(bp), "v"(bp + 2)
            : "memory");
        if (((A.x == want) & (A.z == want)) &
            ((B.x == want) & (B.z == want))) break;
      }
      float4 xv;
      xv.x = __uint_as_float(A.y);
      xv.y = __uint_as_float(A.w);
      xv.z = __uint_as_float(B.y);
      xv.w = __uint_as_float(B.w);
      *(float4*)&x_s[b][(wv << 8) + 4 * l] = xv;  // one ds_write_b128
    }
    __syncthreads();  // barrier 1: all chunks staged

    if (t > 0) {
      const float4* xs4 = (const float4*)x_s[b];
#define ROWFMA(i, di)                            \
      di = fmaf(wreg[i][4*c+0], x4.x, di);       \
      di = fmaf(wreg[i][4*c+1], x4.y, di);       \
      di = fmaf(wreg[i][4*c+2], x4.z, di);       \
      di = fmaf(wreg[i][4*c+3], x4.w, di);
#pragma unroll
      for (int c = 0; c < NCHUNK; ++c) {
        const float4 x4 = xs4[(c << 6) + l];   // ds_read_b128
        ROWFMA(0, d0)
        ROWFMA(1, d1)
        ROWFMA(2, d2)
        ROWFMA(3, d3)
      }
#undef ROWFMA
    }

    // reduce: DPP for intra-16 steps (VALU latency), shuffles only for 16/32.
    float e0 = DPP_ADD(d0, 0xB1);   // quad_perm [1,0,3,2]  (xor 1)
    float e1 = DPP_ADD(d1, 0xB1);
    float e2 = DPP_ADD(d2, 0xB1);
    float e3 = DPP_ADD(d3, 0xB1);
    float f0 = (l & 1) ? e1 : e0;
    float f1 = (l & 1) ? e3 : e2;
    f0 = DPP_ADD(f0, 0x4E);         // quad_perm [2,3,0,1]  (xor 2)
    f1 = DPP_ADD(f1, 0x4E);
    float h = (l & 2) ? f1 : f0;
    h = DPP_ADD(h, 0x124);          // row_ror:4
    h = DPP_ADD(h, 0x128);          // row_ror:8
    h += __shfl_xor(h, 16, 64);
    h += __shfl_xor(h, 32, 64);

    const float ut = u_s[t];
    if (l < ROWS_PER_WAVE) {
      fresh[wv * ROWS_PER_WAVE + l] = tanhf(fmaf(winl, ut, h));
    }
    __syncthreads();  // barrier 2: fresh[] complete

    if (wv == 0) {
      // consolidated publish: one 32-lane 256B store for the whole WG
      if (l < ROWS_PER_WG) {
        const unsigned long long pk =
            ((unsigned long long)__float_as_uint(fresh[l]) << 32) | (unsigned)t;
        __hip_atomic_store(pairs + (t & 1) * HIDDEN + g * ROWS_PER_WG + l, pk,
                           __ATOMIC_RELAXED, __HIP_MEMORY_SCOPE_AGENT);
      }
    } else if (wv == 1 && t >= WASHOUT) {
      // distributed readout: this WG's 32-row partial of x_t . w_out
      float part = (l < 32) ? fresh[l] * wol : 0.f;
      part += __shfl_xor(part, 32, 64);
      part += __shfl_xor(part, 16, 64);
      part += __shfl_xor(part, 8, 64);
      part += __shfl_xor(part, 4, 64);
      part += __shfl_xor(part, 2, 64);
      part += __shfl_xor(part, 1, 64);
      if (l == 0) atomicAdd(&out[t - WASHOUT], part);
    }
  }

  // restore ctl to poison so the next dispatch's claim starts clean.
  // Only workers are alive this late (non-workers exited ~ms ago), and
  // workers never read ctl after the preamble -> race-free in practice.
  if (use_claim && g == 0 && j == 0) {
    __hip_atomic_store(&ctl[0], POISON, __ATOMIC_RELAXED, __HIP_MEMORY_SCOPE_AGENT);
    __hip_atomic_store(&ctl[1], POISON, __ATOMIC_RELAXED, __HIP_MEMORY_SCOPE_AGENT);
  }
}

extern "C" void kernel_launch(void* const* d_in, const int* in_sizes, int n_in,
                              void* d_out, int out_size, void* d_ws, size_t ws_size,
                              hipStream_t stream) {
  const float* u     = (const float*)d_in[0];
  const float* w_in  = (const float*)d_in[1];
  const float* w_res = (const float*)d_in[2];
  const float* w_out = (const float*)d_in[3];
  float* out = (float*)d_out;
  unsigned long long* pairs = (unsigned long long*)d_ws;

  // claim path needs pairs (32 KB) + ctl (8 B) in ws
  const int use_claim = (ws_size >= (size_t)2 * HIDDEN * 8 + 8) ? 1 : 0;
  const int nblk = use_claim ? NBLK_CLAIM : NWG;

  // out accumulates atomicAdd partials -> must start at zero every call
  hipMemsetAsync(out, 0, (size_t)out_size * sizeof(float), stream);
  esn_main<<<nblk, NTHR, 0, stream>>>(u, w_in, w_res, w_out, out, pairs,
                                      use_claim);
}

// Round 4
// 18716.539 us; speedup vs baseline: 3.3217x; 3.3217x over previous
//
#include <hip/hip_runtime.h>

#define HIDDEN   2048
#define T_STEPS  8192
#define WASHOUT  200
#define NWG      64
#define NTHR     512
#define NWAVE    (NTHR / 64)                 // 8 waves
#define ROWS_PER_WG   (HIDDEN / NWG)         // 32
#define ROWS_PER_WAVE (ROWS_PER_WG / NWAVE)  // 4
#define NCHUNK   8                           // 8 chunks of 256 state elements

// ws layout: unsigned long long pairs[2][HIDDEN] -- {value:hi32, step:lo32}.
// One 8B unit carries payload+tag: no fences, no flags, one round trip.
// 0xAA poison: step field 0xAAAAAAAA never matches a real step (self-init).
//
// R17 (this round) -- back to the proven R0 skeleton after R16's spill
// (launch_bounds(512,4) capped regs at 128 -> weight array went to scratch,
// VGPR_Count=64, FETCH 3.9GB). Single-XCD residency is arithmetically dead:
// 2 WGs/CU needs 512KB weights/CU = the whole register file.
// Changes vs R0:
//  (a) barrier1 -> per-chunk LDS flags (acquire/release, WG scope). Waves
//      consume chunks as they are staged, own chunk straight from poll regs.
//      Post-detect tail shrinks from barrier+128 FMA to ~16 FMA + reduce.
//      Weights are loaded PRE-ROTATED (wreg[i][4k+m] = chunk (wv+k)&7) so
//      the unrolled consume loop indexes registers with compile-time k
//      (R16 lesson: runtime-indexed reg arrays spill).
//  (b) publish store carries `nt`: evict the line from writer's L2 toward
//      MALL so readers' post-invalidate refetch skips the dirty-snoop hop.
// Kept: sc1 cacheable polls (R2: nt polls = 1.6x regression), consolidated
// 256B wave-0 publish (R1: scattered publish regressed), VGPR weights (R1:
// VALUBusy halved, harmless).

// DPP add: x + dpp_perm(x). All-VALU (no DS round trip).
#define DPP_ADD(x, ctrl) ((x) + __int_as_float(__builtin_amdgcn_update_dpp( \
    0, __float_as_int(x), ctrl, 0xF, 0xF, true)))

typedef unsigned uint4v __attribute__((ext_vector_type(4)));

// 16 FMAs of chunk-slot kk (compile-time) against x4 (float4)
#define CHUNKFMA(kk, x4)                              \
  d0 = fmaf(wreg[0][4*(kk)+0], (x4).x, d0);           \
  d0 = fmaf(wreg[0][4*(kk)+1], (x4).y, d0);           \
  d0 = fmaf(wreg[0][4*(kk)+2], (x4).z, d0);           \
  d0 = fmaf(wreg[0][4*(kk)+3], (x4).w, d0);           \
  d1 = fmaf(wreg[1][4*(kk)+0], (x4).x, d1);           \
  d1 = fmaf(wreg[1][4*(kk)+1], (x4).y, d1);           \
  d1 = fmaf(wreg[1][4*(kk)+2], (x4).z, d1);           \
  d1 = fmaf(wreg[1][4*(kk)+3], (x4).w, d1);           \
  d2 = fmaf(wreg[2][4*(kk)+0], (x4).x, d2);           \
  d2 = fmaf(wreg[2][4*(kk)+1], (x4).y, d2);           \
  d2 = fmaf(wreg[2][4*(kk)+2], (x4).z, d2);           \
  d2 = fmaf(wreg[2][4*(kk)+3], (x4).w, d2);           \
  d3 = fmaf(wreg[3][4*(kk)+0], (x4).x, d3);           \
  d3 = fmaf(wreg[3][4*(kk)+1], (x4).y, d3);           \
  d3 = fmaf(wreg[3][4*(kk)+2], (x4).z, d3);           \
  d3 = fmaf(wreg[3][4*(kk)+3], (x4).w, d3);

__global__ __launch_bounds__(NTHR, 1) void esn_main(
    const float* __restrict__ u,
    const float* __restrict__ w_in,
    const float* __restrict__ w_res,
    const float* __restrict__ w_out,
    float* __restrict__ out,
    unsigned long long* __restrict__ pairs)
{
  const int g  = blockIdx.x;    // 0..63, one WG per CU
  const int j  = threadIdx.x;   // 0..511
  const int wv = j >> 6;        // 0..7
  const int l  = j & 63;

  __shared__ float x_s[2][HIDDEN];      // double-buffered staged state (16 KB)
  __shared__ float u_s[T_STEPS];        // 32 KB
  __shared__ float fresh[ROWS_PER_WG];  // this WG's newest 32 values
  __shared__ unsigned flg[2][NCHUNK];   // per-chunk stage flags (value = t)

  if (j < 16) flg[j >> 3][j & 7] = 0xFFFFFFFFu;  // != any real t

#pragma unroll
  for (int k = 0; k < T_STEPS / NTHR; ++k) u_s[j + NTHR * k] = u[j + NTHR * k];

  // wave wv owns rows r0..r0+3; lane l owns cols {c*256 + 4l .. +3}
  const int r0 = g * ROWS_PER_WG + wv * ROWS_PER_WAVE;

  // PRE-ROTATED weight load: slot k holds chunk (wv+k)&7, so the consume
  // loop's register index is the compile-time k while the chunk id c is
  // runtime-only in LDS/flag addresses.
  float wreg[ROWS_PER_WAVE][4 * NCHUNK];  // 128 VGPR-resident weights/thread
#pragma unroll
  for (int i = 0; i < ROWS_PER_WAVE; ++i) {
#pragma unroll
    for (int k = 0; k < NCHUNK; ++k) {
      const int c = (wv + k) & 7;
      const float4 a = *(const float4*)&w_res[(r0 + i) * HIDDEN + c * 256 + 4 * l];
      wreg[i][4 * k + 0] = a.x; wreg[i][4 * k + 1] = a.y;
      wreg[i][4 * k + 2] = a.z; wreg[i][4 * k + 3] = a.w;
    }
  }
  // pin weights in VGPRs; value becomes opaque -> no refetch, no remat
#pragma unroll
  for (int i = 0; i < ROWS_PER_WAVE; ++i)
#pragma unroll
    for (int k = 0; k < 4 * NCHUNK; ++k)
      asm volatile("" : "+v"(wreg[i][k]));

  const float winl = w_in[r0 + (l & 3)];                             // lanes 0..3
  const float wol  = (wv == 1 && l < 32) ? w_out[g * 32 + l] : 0.f;  // wave 1

  __syncthreads();  // u_s + flg ready

  for (int t = 0; t < T_STEPS; ++t) {
    float d0 = 0.f, d1 = 0.f, d2 = 0.f, d3 = 0.f;
    const unsigned b = (unsigned)((t - 1) & 1);
    if (t > 0) {
      const unsigned want = (unsigned)(t - 1);
      // wave wv polls only its own chunk; 2x16B sc1 loads (L2-served spin)
      const unsigned long long* bp = pairs + b * HIDDEN + (wv << 8) + 4 * l;
      uint4v A, B;   // [tag0, val0, tag1, val1]
      for (;;) {
        asm volatile(
            "global_load_dwordx4 %0, %2, off sc1\n\t"
            "global_load_dwordx4 %1, %3, off sc1\n\t"
            "s_waitcnt vmcnt(0)"
            : "=&v"(A), "=&v"(B)
            : "v"(bp), "v"(bp + 2)
            : "memory");
        if (((A.x == want) & (A.z == want)) &
            ((B.x == want) & (B.z == want))) break;
      }
      float4 xv;
      xv.x = __uint_as_float(A.y);
      xv.y = __uint_as_float(A.w);
      xv.z = __uint_as_float(B.y);
      xv.w = __uint_as_float(B.w);

      // stage + flag FIRST (unblocks the other 7 waves), then own-chunk FMA
      *(float4*)&x_s[b][(wv << 8) + 4 * l] = xv;  // one ds_write_b128
      __hip_atomic_store(&flg[b][wv], (unsigned)t, __ATOMIC_RELEASE,
                         __HIP_MEMORY_SCOPE_WORKGROUP);

      CHUNKFMA(0, xv)   // own chunk straight from poll registers

#pragma unroll
      for (int k = 1; k < NCHUNK; ++k) {
        const int c = (wv + k) & 7;
        while (__hip_atomic_load(&flg[b][c], __ATOMIC_ACQUIRE,
                                 __HIP_MEMORY_SCOPE_WORKGROUP) != (unsigned)t) {}
        const float4 x4 = *(const float4*)&x_s[b][(c << 8) + 4 * l];
        CHUNKFMA(k, x4)
      }
    }

    // reduce: DPP for intra-16 steps (VALU latency), shuffles only for 16/32.
    float e0 = DPP_ADD(d0, 0xB1);   // quad_perm [1,0,3,2]  (xor 1)
    float e1 = DPP_ADD(d1, 0xB1);
    float e2 = DPP_ADD(d2, 0xB1);
    float e3 = DPP_ADD(d3, 0xB1);
    float f0 = (l & 1) ? e1 : e0;
    float f1 = (l & 1) ? e3 : e2;
    f0 = DPP_ADD(f0, 0x4E);         // quad_perm [2,3,0,1]  (xor 2)
    f1 = DPP_ADD(f1, 0x4E);
    float h = (l & 2) ? f1 : f0;
    h = DPP_ADD(h, 0x124);          // row_ror:4
    h = DPP_ADD(h, 0x128);          // row_ror:8
    h += __shfl_xor(h, 16, 64);
    h += __shfl_xor(h, 32, 64);

    const float ut = u_s[t];
    if (l < ROWS_PER_WAVE) {
      fresh[wv * ROWS_PER_WAVE + l] = tanhf(fmaf(winl, ut, h));
    }
    __syncthreads();  // barrier 2: fresh[] complete; also fences x_s/flg
                      // reuse (parity b recurs only after this barrier x2)

    if (wv == 0) {
      // consolidated publish: one 32-lane 256B store for the whole WG.
      // nt: evict from writer's L2 toward MALL so readers' post-invalidate
      // refetch is a MALL read, not a dirty-line snoop of this L2.
      if (l < ROWS_PER_WG) {
        const unsigned long long pk =
            ((unsigned long long)__float_as_uint(fresh[l]) << 32) | (unsigned)t;
        unsigned long long* pa = pairs + (t & 1) * HIDDEN + g * ROWS_PER_WG + l;
        asm volatile("global_store_dwordx2 %0, %1, off sc1 nt"
                     :: "v"(pa), "v"(pk) : "memory");
      }
    } else if (wv == 1 && t >= WASHOUT) {
      // distributed readout: this WG's 32-row partial of x_t . w_out
      float part = (l < 32) ? fresh[l] * wol : 0.f;
      part += __shfl_xor(part, 32, 64);
      part += __shfl_xor(part, 16, 64);
      part += __shfl_xor(part, 8, 64);
      part += __shfl_xor(part, 4, 64);
      part += __shfl_xor(part, 2, 64);
      part += __shfl_xor(part, 1, 64);
      if (l == 0) atomicAdd(&out[t - WASHOUT], part);
    }
  }
}

extern "C" void kernel_launch(void* const* d_in, const int* in_sizes, int n_in,
                              void* d_out, int out_size, void* d_ws, size_t ws_size,
                              hipStream_t stream) {
  const float* u     = (const float*)d_in[0];
  const float* w_in  = (const float*)d_in[1];
  const float* w_res = (const float*)d_in[2];
  const float* w_out = (const float*)d_in[3];
  float* out = (float*)d_out;
  unsigned long long* pairs = (unsigned long long*)d_ws;

  // out accumulates atomicAdd partials -> must start at zero every call
  hipMemsetAsync(out, 0, (size_t)out_size * sizeof(float), stream);
  esn_main<<<NWG, NTHR, 0, stream>>>(u, w_in, w_res, w_out, out, pairs);
}

// Round 5
// 16246.533 us; speedup vs baseline: 3.8267x; 1.1520x over previous
//
#include <hip/hip_runtime.h>

#define HIDDEN   2048
#define T_STEPS  8192
#define WASHOUT  200
#define NWG      64
#define NTHR     512
#define NWAVE    (NTHR / 64)                 // 8 waves
#define ROWS_PER_WG   (HIDDEN / NWG)         // 32
#define ROWS_PER_WAVE (ROWS_PER_WG / NWAVE)  // 4
#define NCHUNK   8                           // 8 chunks of 256 state elements
#define NREPL    8                           // one mailbox replica per XCD
#define REPL     (2 * HIDDEN)                // ull elements per replica (32 KB)

// ws layout: NREPL replicas of {unsigned long long pairs[2][HIDDEN]}.
// Pair = {value:hi32, step:lo32}: one 8B unit carries payload+tag.
// 0xAA poison: tag 0xAAAAAAAA never matches a real step; stale tags from a
// previous dispatch (<=8191) are overwritten thousands of steps before the
// want sequence reaches them -> self-correcting across graph replays.
//
// R18 (this round): PER-XCD MAILBOX REPLICAS. Four rounds of evidence say
// the step time is store -> cross-XCD visibility -> refetch (~1.4us of
// 2.15us): polls are local-L2-served (R2 FETCH signature), so ONE agent
// store must probe/invalidate stale copies of the same line in up to 8
// remote L2s before readers refetch from MALL. Replicas make each mailbox
// line cacheable in exactly ONE L2: writer stores its 256B to 8 disjoint
// per-XCD regions (independent pipelined full-line stores -- NOT R1's
// scattered partial-line pattern); readers poll replica[XCC_ID] only.
// Probe fan-out 8 -> 1. Everything else = exact R0 skeleton:
//  - two barriers (R4: LDS-flag chunk pipeline regressed)
//  - consolidated wave-0 publish (R1: per-wave scatter regressed)
//  - sc1 cacheable polls, NO nt anywhere (R2: nt polls 1.6x; R4: nt store)
//  - VGPR-resident pinned weights (R1: halves VALU issue, never spills
//    at launch_bounds(512,1); R3: bounds 4 -> scratch disaster)

// DPP add: x + dpp_perm(x). All-VALU (no DS round trip).
#define DPP_ADD(x, ctrl) ((x) + __int_as_float(__builtin_amdgcn_update_dpp( \
    0, __float_as_int(x), ctrl, 0xF, 0xF, true)))

typedef unsigned uint4v __attribute__((ext_vector_type(4)));

__global__ __launch_bounds__(NTHR, 1) void esn_main(
    const float* __restrict__ u,
    const float* __restrict__ w_in,
    const float* __restrict__ w_res,
    const float* __restrict__ w_out,
    float* __restrict__ out,
    unsigned long long* __restrict__ pairs,
    int nrepl)
{
  const int g  = blockIdx.x;    // 0..63, one WG per CU
  const int j  = threadIdx.x;   // 0..511
  const int wv = j >> 6;        // 0..7
  const int l  = j & 63;

  // which XCD am I on? poll only that replica. Uniform per wave (SGPR).
  unsigned xcc;
  asm("s_getreg_b32 %0, hwreg(HW_REG_XCC_ID)" : "=s"(xcc));
  const unsigned ri = xcc & (unsigned)(nrepl - 1);   // nrepl is 1 or 8
  unsigned long long* __restrict__ myrep = pairs + (size_t)ri * REPL;

  __shared__ float x_s[2][HIDDEN];      // double-buffered staged state (16 KB)
  __shared__ float u_s[T_STEPS];        // 32 KB
  __shared__ float fresh[ROWS_PER_WG];  // this WG's newest 32 values

#pragma unroll
  for (int k = 0; k < T_STEPS / NTHR; ++k) u_s[j + NTHR * k] = u[j + NTHR * k];

  // wave wv owns rows r0..r0+3; lane l owns cols {c*256 + 4l .. +3}
  const int r0 = g * ROWS_PER_WG + wv * ROWS_PER_WAVE;

  float wreg[ROWS_PER_WAVE][4 * NCHUNK];  // 128 VGPR-resident weights/thread
#pragma unroll
  for (int i = 0; i < ROWS_PER_WAVE; ++i) {
#pragma unroll
    for (int c = 0; c < NCHUNK; ++c) {
      const float4 a = *(const float4*)&w_res[(r0 + i) * HIDDEN + c * 256 + 4 * l];
      wreg[i][4 * c + 0] = a.x; wreg[i][4 * c + 1] = a.y;
      wreg[i][4 * c + 2] = a.z; wreg[i][4 * c + 3] = a.w;
    }
  }
  // pin weights in VGPRs; value becomes opaque -> no refetch, no remat
#pragma unroll
  for (int i = 0; i < ROWS_PER_WAVE; ++i)
#pragma unroll
    for (int k = 0; k < 4 * NCHUNK; ++k)
      asm volatile("" : "+v"(wreg[i][k]));

  const float winl = w_in[r0 + (l & 3)];                             // lanes 0..3
  const float wol  = (wv == 1 && l < 32) ? w_out[g * 32 + l] : 0.f;  // wave 1

  __syncthreads();  // u_s ready

  for (int t = 0; t < T_STEPS; ++t) {
    float d0 = 0.f, d1 = 0.f, d2 = 0.f, d3 = 0.f;
    const unsigned b = (unsigned)((t - 1) & 1);
    if (t > 0) {
      const unsigned want = (unsigned)(t - 1);
      // wave wv polls only its own chunk OF ITS XCD'S REPLICA;
      // 2x16B sc1 loads -> spin served from the local L2.
      const unsigned long long* bp = myrep + b * HIDDEN + (wv << 8) + 4 * l;
      uint4v A, B;   // [tag0, val0, tag1, val1]
      for (;;) {
        asm volatile(
            "global_load_dwordx4 %0, %2, off sc1\n\t"
            "global_load_dwordx4 %1, %3, off sc1\n\t"
            "s_waitcnt vmcnt(0)"
            : "=&v"(A), "=&v"(B)
            : "v"(bp), "v"(bp + 2)
            : "memory");
        if (((A.x == want) & (A.z == want)) &
            ((B.x == want) & (B.z == want))) break;
      }
      float4 xv;
      xv.x = __uint_as_float(A.y);
      xv.y = __uint_as_float(A.w);
      xv.z = __uint_as_float(B.y);
      xv.w = __uint_as_float(B.w);
      *(float4*)&x_s[b][(wv << 8) + 4 * l] = xv;  // one ds_write_b128
    }
    __syncthreads();  // barrier 1: all chunks staged

    if (t > 0) {
      const float4* xs4 = (const float4*)x_s[b];
#define ROWFMA(i, di)                            \
      di = fmaf(wreg[i][4*c+0], x4.x, di);       \
      di = fmaf(wreg[i][4*c+1], x4.y, di);       \
      di = fmaf(wreg[i][4*c+2], x4.z, di);       \
      di = fmaf(wreg[i][4*c+3], x4.w, di);
#pragma unroll
      for (int c = 0; c < NCHUNK; ++c) {
        const float4 x4 = xs4[(c << 6) + l];   // ds_read_b128
        ROWFMA(0, d0)
        ROWFMA(1, d1)
        ROWFMA(2, d2)
        ROWFMA(3, d3)
      }
#undef ROWFMA
    }

    // reduce: DPP for intra-16 steps (VALU latency), shuffles only for 16/32.
    float e0 = DPP_ADD(d0, 0xB1);   // quad_perm [1,0,3,2]  (xor 1)
    float e1 = DPP_ADD(d1, 0xB1);
    float e2 = DPP_ADD(d2, 0xB1);
    float e3 = DPP_ADD(d3, 0xB1);
    float f0 = (l & 1) ? e1 : e0;
    float f1 = (l & 1) ? e3 : e2;
    f0 = DPP_ADD(f0, 0x4E);         // quad_perm [2,3,0,1]  (xor 2)
    f1 = DPP_ADD(f1, 0x4E);
    float h = (l & 2) ? f1 : f0;
    h = DPP_ADD(h, 0x124);          // row_ror:4
    h = DPP_ADD(h, 0x128);          // row_ror:8
    h += __shfl_xor(h, 16, 64);
    h += __shfl_xor(h, 32, 64);

    const float ut = u_s[t];
    if (l < ROWS_PER_WAVE) {
      fresh[wv * ROWS_PER_WAVE + l] = tanhf(fmaf(winl, ut, h));
    }
    __syncthreads();  // barrier 2: fresh[] complete

    if (wv == 0) {
      // consolidated publish, fanned out to every XCD's replica: nrepl
      // independent 32-lane 256B full-line stores (pipelined in the vmem
      // queue; each invalidates copies in exactly ONE remote L2).
      if (l < ROWS_PER_WG) {
        const unsigned long long pk =
            ((unsigned long long)__float_as_uint(fresh[l]) << 32) | (unsigned)t;
        unsigned long long* base =
            pairs + (t & 1) * HIDDEN + g * ROWS_PER_WG + l;
        for (int r = 0; r < nrepl; ++r) {
          __hip_atomic_store(base + (size_t)r * REPL, pk,
                             __ATOMIC_RELAXED, __HIP_MEMORY_SCOPE_AGENT);
        }
      }
    } else if (wv == 1 && t >= WASHOUT) {
      // distributed readout: this WG's 32-row partial of x_t . w_out
      float part = (l < 32) ? fresh[l] * wol : 0.f;
      part += __shfl_xor(part, 32, 64);
      part += __shfl_xor(part, 16, 64);
      part += __shfl_xor(part, 8, 64);
      part += __shfl_xor(part, 4, 64);
      part += __shfl_xor(part, 2, 64);
      part += __shfl_xor(part, 1, 64);
      if (l == 0) atomicAdd(&out[t - WASHOUT], part);
    }
  }
}

extern "C" void kernel_launch(void* const* d_in, const int* in_sizes, int n_in,
                              void* d_out, int out_size, void* d_ws, size_t ws_size,
                              hipStream_t stream) {
  const float* u     = (const float*)d_in[0];
  const float* w_in  = (const float*)d_in[1];
  const float* w_res = (const float*)d_in[2];
  const float* w_out = (const float*)d_in[3];
  float* out = (float*)d_out;
  unsigned long long* pairs = (unsigned long long*)d_ws;

  // replicas need NREPL * 32 KB of ws; fall back to a single mailbox
  const int nrepl =
      (ws_size >= (size_t)NREPL * REPL * sizeof(unsigned long long)) ? NREPL : 1;

  // out accumulates atomicAdd partials -> must start at zero every call
  hipMemsetAsync(out, 0, (size_t)out_size * sizeof(float), stream);
  esn_main<<<NWG, NTHR, 0, stream>>>(u, w_in, w_res, w_out, out, pairs, nrepl);
}

// Round 7
// 14059.131 us; speedup vs baseline: 4.4221x; 1.1556x over previous
//
#include <hip/hip_runtime.h>

#define HIDDEN   2048
#define T_STEPS  8192
#define WASHOUT  200
#define NWG      64
#define NTHR     512
#define NWAVE    (NTHR / 64)                 // 8 waves
#define ROWS_PER_WG   (HIDDEN / NWG)         // 32
#define ROWS_PER_WAVE (ROWS_PER_WG / NWAVE)  // 4
#define NCHUNK   8                           // 8 chunks of 256 state elements
#define NREPL    8                           // one mailbox replica per XCD
#define REPL     (2 * HIDDEN)                // ull elements per replica (32 KB)

// ws layout: NREPL replicas of {unsigned long long pairs[2][HIDDEN]}.
// Pair = {value:hi32, step:lo32}: one 8B unit carries payload+tag.
// 0xAA poison tags self-correct across graph replays.
//
// R20 (this round): re-land R19 with the permlane bug fixed. R19 FAILED
// (absmax 1.68) because the self-swap was written as inline asm with two
// "+v" operands holding the SAME value -- the allocator coalesced them into
// one register, turning the swap into v_permlane16_swap v0,v0 and the sum
// into 2*h^16. Fix: use __builtin_amdgcn_permlane{16,32}_swap, which
// returns BOTH outputs as a uint2 (distinct result registers guaranteed);
// sum .x+.y is correct under either exchange direction. __has_builtin
// guard falls back to the proven __shfl_xor.
// Re-landed from R19 (analytically safe, never actually bench-isolated):
//  (b) fast tanh 1-2/(e^{2x}+1) via raw v_exp_f32+v_rcp_f32 (~25cy vs
//      ~60-100cy ocml tanhf; saturates correctly; ~1e-6 abs err).
//  (c) per-wave replica publish: wave w stores replica w (8 parallel 256B
//      full-line stores instead of an 8-store burst on wave 0). Protocol
//      invariant unchanged: overwrite of slot t at t+2 transitively
//      requires every reader consumed t (2-step distance, per-wave).
// Kept from R18/R0: sc1 cacheable polls, NO nt anywhere, full-line
// publishes, VGPR-pinned weights, two barriers, launch_bounds(512,1).

// DPP add: x + dpp_perm(x). All-VALU (no DS round trip).
#define DPP_ADD(x, ctrl) ((x) + __int_as_float(__builtin_amdgcn_update_dpp( \
    0, __float_as_int(x), ctrl, 0xF, 0xF, true)))

typedef unsigned uint4v __attribute__((ext_vector_type(4)));

__global__ __launch_bounds__(NTHR, 1) void esn_main(
    const float* __restrict__ u,
    const float* __restrict__ w_in,
    const float* __restrict__ w_res,
    const float* __restrict__ w_out,
    float* __restrict__ out,
    unsigned long long* __restrict__ pairs,
    int nrepl)
{
  const int g  = blockIdx.x;    // 0..63, one WG per CU
  const int j  = threadIdx.x;   // 0..511
  const int wv = j >> 6;        // 0..7
  const int l  = j & 63;

  // which XCD am I on? poll only that replica. Uniform per wave (SGPR).
  unsigned xcc;
  asm("s_getreg_b32 %0, hwreg(HW_REG_XCC_ID)" : "=s"(xcc));
  const unsigned ri = xcc & (unsigned)(nrepl - 1);   // nrepl is 1 or 8
  unsigned long long* __restrict__ myrep = pairs + (size_t)ri * REPL;

  __shared__ float x_s[2][HIDDEN];      // double-buffered staged state (16 KB)
  __shared__ float u_s[T_STEPS];        // 32 KB
  __shared__ float fresh[ROWS_PER_WG];  // this WG's newest 32 values

#pragma unroll
  for (int k = 0; k < T_STEPS / NTHR; ++k) u_s[j + NTHR * k] = u[j + NTHR * k];

  // wave wv owns rows r0..r0+3; lane l owns cols {c*256 + 4l .. +3}
  const int r0 = g * ROWS_PER_WG + wv * ROWS_PER_WAVE;

  float wreg[ROWS_PER_WAVE][4 * NCHUNK];  // 128 VGPR-resident weights/thread
#pragma unroll
  for (int i = 0; i < ROWS_PER_WAVE; ++i) {
#pragma unroll
    for (int c = 0; c < NCHUNK; ++c) {
      const float4 a = *(const float4*)&w_res[(r0 + i) * HIDDEN + c * 256 + 4 * l];
      wreg[i][4 * c + 0] = a.x; wreg[i][4 * c + 1] = a.y;
      wreg[i][4 * c + 2] = a.z; wreg[i][4 * c + 3] = a.w;
    }
  }
  // pin weights in VGPRs; value becomes opaque -> no refetch, no remat
#pragma unroll
  for (int i = 0; i < ROWS_PER_WAVE; ++i)
#pragma unroll
    for (int k = 0; k < 4 * NCHUNK; ++k)
      asm volatile("" : "+v"(wreg[i][k]));

  const float winl = w_in[r0 + (l & 3)];                             // lanes 0..3
  const float wol  = (wv == 1 && l < 32) ? w_out[g * 32 + l] : 0.f;  // wave 1

  __syncthreads();  // u_s ready

  for (int t = 0; t < T_STEPS; ++t) {
    float d0 = 0.f, d1 = 0.f, d2 = 0.f, d3 = 0.f;
    const unsigned b = (unsigned)((t - 1) & 1);
    if (t > 0) {
      const unsigned want = (unsigned)(t - 1);
      // wave wv polls only its own chunk OF ITS XCD'S REPLICA;
      // 2x16B sc1 loads -> spin served from the local L2.
      const unsigned long long* bp = myrep + b * HIDDEN + (wv << 8) + 4 * l;
      uint4v A, B;   // [tag0, val0, tag1, val1]
      for (;;) {
        asm volatile(
            "global_load_dwordx4 %0, %2, off sc1\n\t"
            "global_load_dwordx4 %1, %3, off sc1\n\t"
            "s_waitcnt vmcnt(0)"
            : "=&v"(A), "=&v"(B)
            : "v"(bp), "v"(bp + 2)
            : "memory");
        if (((A.x == want) & (A.z == want)) &
            ((B.x == want) & (B.z == want))) break;
      }
      float4 xv;
      xv.x = __uint_as_float(A.y);
      xv.y = __uint_as_float(A.w);
      xv.z = __uint_as_float(B.y);
      xv.w = __uint_as_float(B.w);
      *(float4*)&x_s[b][(wv << 8) + 4 * l] = xv;  // one ds_write_b128
    }
    __syncthreads();  // barrier 1: all chunks staged

    if (t > 0) {
      const float4* xs4 = (const float4*)x_s[b];
#define ROWFMA(i, di)                            \
      di = fmaf(wreg[i][4*c+0], x4.x, di);       \
      di = fmaf(wreg[i][4*c+1], x4.y, di);       \
      di = fmaf(wreg[i][4*c+2], x4.z, di);       \
      di = fmaf(wreg[i][4*c+3], x4.w, di);
#pragma unroll
      for (int c = 0; c < NCHUNK; ++c) {
        const float4 x4 = xs4[(c << 6) + l];   // ds_read_b128
        ROWFMA(0, d0)
        ROWFMA(1, d1)
        ROWFMA(2, d2)
        ROWFMA(3, d3)
      }
#undef ROWFMA
    }

    // reduce: DPP for intra-16 steps; permlane swaps (pure VALU, no LDS
    // round trip) for the 16/32 cross-group steps.
    float e0 = DPP_ADD(d0, 0xB1);   // quad_perm [1,0,3,2]  (xor 1)
    float e1 = DPP_ADD(d1, 0xB1);
    float e2 = DPP_ADD(d2, 0xB1);
    float e3 = DPP_ADD(d3, 0xB1);
    float f0 = (l & 1) ? e1 : e0;
    float f1 = (l & 1) ? e3 : e2;
    f0 = DPP_ADD(f0, 0x4E);         // quad_perm [2,3,0,1]  (xor 2)
    f1 = DPP_ADD(f1, 0x4E);
    float h = (l & 2) ? f1 : f0;
    h = DPP_ADD(h, 0x124);          // row_ror:4
    h = DPP_ADD(h, 0x128);          // row_ror:8
#if __has_builtin(__builtin_amdgcn_permlane16_swap) && \
    __has_builtin(__builtin_amdgcn_permlane32_swap)
    {
      // h += h^16 then h += h^32. Builtin returns BOTH outputs (uint2) ->
      // distinct registers guaranteed (R19's asm self-swap coalesced the
      // two "+v" operands into one reg and corrupted the sums).
      typedef unsigned uint2v __attribute__((ext_vector_type(2)));
      uint2v s16 = __builtin_amdgcn_permlane16_swap(
          __float_as_uint(h), __float_as_uint(h), false, false);
      h = __uint_as_float(s16.x) + __uint_as_float(s16.y);
      uint2v s32 = __builtin_amdgcn_permlane32_swap(
          __float_as_uint(h), __float_as_uint(h), false, false);
      h = __uint_as_float(s32.x) + __uint_as_float(s32.y);
    }
#else
    h += __shfl_xor(h, 16, 64);
    h += __shfl_xor(h, 32, 64);
#endif

    const float ut = u_s[t];
    if (l < ROWS_PER_WAVE) {
      // fast tanh: 1 - 2/(e^{2x}+1) via v_exp_f32 (2^x) + v_rcp_f32;
      // saturates correctly via exp overflow/underflow; ~1e-6 abs err.
      const float a = fmaf(winl, ut, h);
      float z;
      asm("v_exp_f32 %0, %1" : "=v"(z) : "v"(a * 2.885390082f));
      float r;
      asm("v_rcp_f32 %0, %1" : "=v"(r) : "v"(z + 1.0f));
      fresh[wv * ROWS_PER_WAVE + l] = fmaf(-2.0f, r, 1.0f);
    }
    __syncthreads();  // barrier 2: fresh[] complete

    // per-wave replica publish: wave wv stores the WG's full 32-row slice
    // to replica wv (8 parallel 256B full-line stores across the waves).
    if (wv < nrepl && l < ROWS_PER_WG) {
      const unsigned long long pk =
          ((unsigned long long)__float_as_uint(fresh[l]) << 32) | (unsigned)t;
      __hip_atomic_store(
          pairs + (size_t)wv * REPL + (t & 1) * HIDDEN + g * ROWS_PER_WG + l,
          pk, __ATOMIC_RELAXED, __HIP_MEMORY_SCOPE_AGENT);
    }
    if (wv == 1 && t >= WASHOUT) {
      // distributed readout: this WG's 32-row partial of x_t . w_out
      float part = (l < 32) ? fresh[l] * wol : 0.f;
      part += __shfl_xor(part, 32, 64);
      part += __shfl_xor(part, 16, 64);
      part += __shfl_xor(part, 8, 64);
      part += __shfl_xor(part, 4, 64);
      part += __shfl_xor(part, 2, 64);
      part += __shfl_xor(part, 1, 64);
      if (l == 0) atomicAdd(&out[t - WASHOUT], part);
    }
  }
}

extern "C" void kernel_launch(void* const* d_in, const int* in_sizes, int n_in,
                              void* d_out, int out_size, void* d_ws, size_t ws_size,
                              hipStream_t stream) {
  const float* u     = (const float*)d_in[0];
  const float* w_in  = (const float*)d_in[1];
  const float* w_res = (const float*)d_in[2];
  const float* w_out = (const float*)d_in[3];
  float* out = (float*)d_out;
  unsigned long long* pairs = (unsigned long long*)d_ws;

  // replicas need NREPL * 32 KB of ws; fall back to a single mailbox
  const int nrepl =
      (ws_size >= (size_t)NREPL * REPL * sizeof(unsigned long long)) ? NREPL : 1;

  // out accumulates atomicAdd partials -> must start at zero every call
  hipMemsetAsync(out, 0, (size_t)out_size * sizeof(float), stream);
  esn_main<<<NWG, NTHR, 0, stream>>>(u, w_in, w_res, w_out, out, pairs, nrepl);
}